// Round 11
// baseline (381.258 us; speedup 1.0000x reference)
//
#include <hip/hip_runtime.h>

#define B_ 8
#define C_ 256
#define I_ 128
#define N_ 4096
#define BN_ (B_ * N_)
#define LOG2E 1.4426950408889634f

typedef __attribute__((ext_vector_type(8))) short bf16x8;
typedef __attribute__((ext_vector_type(4))) float f32x4;
typedef __attribute__((ext_vector_type(4))) int i32x4;

static __device__ __forceinline__ short f2bf(float f) {
    unsigned u = __float_as_uint(f);
    unsigned r = u + 0x7fffu + ((u >> 16) & 1u);  // RNE
    return (short)(r >> 16);
}
static __device__ __forceinline__ float bf2f(short s) {
    return __uint_as_float(((unsigned)(unsigned short)s) << 16);
}
static __device__ __forceinline__ unsigned cvt_pk_bf16(float lo, float hi) {
    unsigned r;
    asm("v_cvt_pk_bf16_f32 %0, %1, %2" : "=v"(r) : "v"(lo), "v"(hi));
    return r;
}

// ---------------- K0: weight prep (theta scaled by log2e) ----------------
__global__ void k_prep(const float* g_w, const float* theta_w, const float* phi_w,
                       const float* g_b, const float* theta_b, const float* phi_b,
                       const float* w_w, short* wcat, short* wwb, float* bcat) {
    int i = blockIdx.x * 256 + threadIdx.x;
    if (i < 384 * 256) {
        int j = i >> 8, c = i & 255;
        float v = (j < 128) ? theta_w[j * 256 + c] * LOG2E
                : (j < 256) ? phi_w[(j - 128) * 256 + c]
                            : g_w[(j - 256) * 256 + c];
        wcat[i] = f2bf(v);
    } else if (i < 384 * 256 + 256 * 128) {
        int k = i - 384 * 256;
        wwb[k] = f2bf(w_w[k]);
    } else if (i < 384 * 256 + 256 * 128 + 384) {
        int j = i - (384 * 256 + 256 * 128);
        bcat[j] = (j < 128) ? theta_b[j] * LOG2E
                : (j < 256) ? phi_b[j - 128] : g_b[j - 256];
    }
}

// ---------------- K1: projection -> tp[B][N][256], gmat[B][I][N] -------------
// (R10-verified version)
__global__ __launch_bounds__(256) void k_proj(const float* __restrict__ x,
                                              const short* __restrict__ wcat,
                                              const float* __restrict__ bcat,
                                              short* __restrict__ tp,
                                              short* __restrict__ gmat) {
    int b = blockIdx.y;
    int n0 = blockIdx.x * 64;
    int tid = threadIdx.x;
    int wave = tid >> 6, lane = tid & 63, s = lane & 15, q = lane >> 4;
    __shared__ __align__(16) char SM[33024];  // xs[64][258] | ytile | gtile
    short (*xs)[258] = (short(*)[258])SM;

#pragma unroll
    for (int it = 0; it < 16; ++it) {
        int cr = (tid >> 4) + it * 16;
        int nc = tid & 15;
        const float4 v = *(const float4*)&x[((size_t)b * C_ + cr) * N_ + n0 + nc * 4];
        xs[nc * 4 + 0][cr] = f2bf(v.x);
        xs[nc * 4 + 1][cr] = f2bf(v.y);
        xs[nc * 4 + 2][cr] = f2bf(v.z);
        xs[nc * 4 + 3][cr] = f2bf(v.w);
    }
    __syncthreads();

    f32x4 acc[4][6];
#pragma unroll
    for (int rt = 0; rt < 4; ++rt)
#pragma unroll
        for (int jt = 0; jt < 6; ++jt) acc[rt][jt] = (f32x4){0.f, 0.f, 0.f, 0.f};

#pragma unroll
    for (int kb = 0; kb < 8; ++kb) {
        bf16x8 af[4], bfv[6];
#pragma unroll
        for (int rt = 0; rt < 4; ++rt)
            af[rt] = *(const bf16x8*)&xs[rt * 16 + s][kb * 32 + q * 8];
#pragma unroll
        for (int jt = 0; jt < 6; ++jt)
            bfv[jt] = *(const bf16x8*)&wcat[(wave * 96 + jt * 16 + s) * 256 + kb * 32 + q * 8];
#pragma unroll
        for (int rt = 0; rt < 4; ++rt)
#pragma unroll
            for (int jt = 0; jt < 6; ++jt)
                acc[rt][jt] = __builtin_amdgcn_mfma_f32_16x16x32_bf16(af[rt], bfv[jt], acc[rt][jt], 0, 0, 0);
    }
    __syncthreads();  // xs dead; reuse SM

    // ---- Phase A: tp (j < 256) via ytile[64][256] bounce ----
    short* ytile = (short*)SM;
#pragma unroll
    for (int jt = 0; jt < 6; ++jt) {
        int j = wave * 96 + jt * 16 + s;
        if (j < 256) {
            float bias = bcat[j];
#pragma unroll
            for (int rt = 0; rt < 4; ++rt)
#pragma unroll
                for (int r = 0; r < 4; ++r)
                    ytile[(rt * 16 + 4 * q + r) * 256 + j] = f2bf(acc[rt][jt][r] + bias);
        }
    }
    __syncthreads();
    {
        short* dst = tp + ((size_t)b * N_ + n0) * 256;
#pragma unroll
        for (int k = 0; k < 8; ++k) {
            int off = k * 2048 + tid * 8;
            *(bf16x8*)(dst + off) = *(const bf16x8*)(ytile + off);
        }
    }
    __syncthreads();

    // ---- Phase B: gmat (j >= 256) via gtile[128][66] bounce ----
    short* gt = (short*)SM;
#pragma unroll
    for (int jt = 0; jt < 6; ++jt) {
        int j = wave * 96 + jt * 16 + s;
        if (j >= 256) {
            float bias = bcat[j];
            int i2 = j - 256;
#pragma unroll
            for (int rt = 0; rt < 4; ++rt)
#pragma unroll
                for (int r = 0; r < 4; ++r)
                    gt[i2 * 66 + rt * 16 + 4 * q + r] = f2bf(acc[rt][jt][r] + bias);
        }
    }
    __syncthreads();
#pragma unroll
    for (int k = 0; k < 4; ++k) {
        int idx = k * 256 + tid;      // 1024 chunks of 8 shorts
        int i2 = idx >> 3, nch = idx & 7;
        bf16x8 v = *(const bf16x8*)(gt + i2 * 66 + nch * 8);
        *(bf16x8*)&gmat[((size_t)b * I_ + i2) * N_ + n0 + nch * 8] = v;
    }
}

// ---- K2: L2-direct fused flash attention + conv-out GEMM --------------------
// 256 blocks x 512 threads (1 block/CU, 8 waves). NO LDS staging, NO barriers
// in the main loop: per-b K/V (tp-phi 1MB + gmat 1MB) fits the XCD's 4MB L2,
// and b=id&7 pins same-b blocks to one XCD. Waves free-run: 4 qg (32 q, fr=2)
// x 2 kg (2048-key half), 64 keys/step read as b128 fragments from L2.
// Epilogue (LDS): kg cross-reduction -> y bf16 -> wy GEMM -> wyh; BN stats
// written per-block NON-atomically to bnpart (k_fin reduces).
__global__ __launch_bounds__(512, 2) void k_attn_wy(const short* __restrict__ tp,
                                                    const short* __restrict__ gmat,
                                                    const short* __restrict__ wwb,
                                                    const float* __restrict__ w_b,
                                                    short* __restrict__ wyh,
                                                    float* __restrict__ bnpart) {
    int id = blockIdx.x;
    int b = id & 7;               // XCD swizzle: one batch's K/V per XCD L2
    int qt = id >> 3;             // 0..31
    int n0 = qt * 128;
    int tid = threadIdx.x;
    int wave = tid >> 6, lane = tid & 63, s = lane & 15, q = lane >> 4;
    int kg = wave >> 2, qg = wave & 3;

    __shared__ __align__(16) short SH[49152];   // 96KB: O-dump 64K | y 32K
    __shared__ float l_lds[2][128];
    char* base = (char*)SH;
    const int swz = (s & 7) << 4;
    int kA[4];   // for wy-GEMM y reads (same swizzle as y writes)
#pragma unroll
    for (int kb = 0; kb < 4; ++kb) kA[kb] = s * 256 + ((kb * 64 + q * 16) ^ swz);

    // ones B-frag for l-accumulation MFMA
    i32x4 onesw = (i32x4){0x3F803F80, 0x3F803F80, 0x3F803F80, 0x3F803F80};
    bf16x8 vone = __builtin_bit_cast(bf16x8, onesw);

    // Q fragments (B-operand of S^T): queries n0 + qg*32 + fr*16 + s
    bf16x8 qf[2][4];
#pragma unroll
    for (int fr = 0; fr < 2; ++fr) {
        const short* qb = tp + ((size_t)b * N_ + n0 + qg * 32 + fr * 16 + s) * 256;
#pragma unroll
        for (int kb = 0; kb < 4; ++kb) qf[fr][kb] = *(const bf16x8*)(qb + kb * 32 + q * 8);
    }

    // per-wave L2 base pointers (lane-resolved)
    const short* kTp = tp + ((size_t)b * N_ + kg * 2048 + s) * 256 + 128 + q * 8;
    const short* vGp = gmat + ((size_t)b * I_ + s) * N_ + kg * 2048 + q * 8;

    f32x4 ot[2][8];
#pragma unroll
    for (int fr = 0; fr < 2; ++fr)
#pragma unroll
        for (int t = 0; t < 8; ++t) ot[fr][t] = (f32x4){0.f, 0.f, 0.f, 0.f};
    f32x4 lacc[2] = {(f32x4){0.f, 0.f, 0.f, 0.f}, (f32x4){0.f, 0.f, 0.f, 0.f}};

    for (int step = 0; step < 32; ++step) {
        int mloc = step * 64;

        // S^T = mfma(K, Q): K fragments straight from L2
        f32x4 sa[2][4];
#pragma unroll
        for (int fr = 0; fr < 2; ++fr)
#pragma unroll
            for (int tc = 0; tc < 4; ++tc) sa[fr][tc] = (f32x4){0.f, 0.f, 0.f, 0.f};
        __builtin_amdgcn_s_setprio(1);
#pragma unroll
        for (int tc = 0; tc < 4; ++tc) {
            const short* kp = kTp + (size_t)(mloc + tc * 16) * 256;
            bf16x8 kf[4];
#pragma unroll
            for (int kb = 0; kb < 4; ++kb) kf[kb] = *(const bf16x8*)(kp + kb * 32);
#pragma unroll
            for (int fr = 0; fr < 2; ++fr)
#pragma unroll
                for (int kb = 0; kb < 4; ++kb)
                    sa[fr][tc] = __builtin_amdgcn_mfma_f32_16x16x32_bf16(kf[kb], qf[fr][kb], sa[fr][tc], 0, 0, 0);
        }
        __builtin_amdgcn_s_setprio(0);

        // P = exp2(S), pack pairs
        unsigned W[2][4][2];
#pragma unroll
        for (int fr = 0; fr < 2; ++fr) {
#pragma unroll
            for (int tc = 0; tc < 4; ++tc)
#pragma unroll
                for (int r = 0; r < 4; ++r) sa[fr][tc][r] = exp2f(sa[fr][tc][r]);
#pragma unroll
            for (int tc = 0; tc < 4; ++tc) {
                W[fr][tc][0] = cvt_pk_bf16(sa[fr][tc][0], sa[fr][tc][1]);
                W[fr][tc][1] = cvt_pk_bf16(sa[fr][tc][2], sa[fr][tc][3]);
            }
        }

        // build PV A-frags (both kb2) via permlane swaps
        bf16x8 pa[2][2];  // [fr][kb2]
#pragma unroll
        for (int kb2 = 0; kb2 < 2; ++kb2)
#pragma unroll
            for (int fr = 0; fr < 2; ++fr) {
                unsigned rA = W[fr][2 * kb2 + 0][0];
                unsigned rB = W[fr][2 * kb2 + 0][1];
                unsigned rC = W[fr][2 * kb2 + 1][0];
                unsigned rD = W[fr][2 * kb2 + 1][1];
                asm("v_permlane32_swap_b32 %0, %1" : "+v"(rA), "+v"(rC));
                asm("v_permlane32_swap_b32 %0, %1" : "+v"(rB), "+v"(rD));
                asm("v_permlane16_swap_b32 %0, %1" : "+v"(rA), "+v"(rC));
                asm("v_permlane16_swap_b32 %0, %1" : "+v"(rB), "+v"(rD));
                i32x4 wv = (i32x4){(int)rA, (int)rB, (int)rC, (int)rD};
                pa[fr][kb2] = __builtin_bit_cast(bf16x8, wv);
            }

        __builtin_amdgcn_s_setprio(1);
        lacc[0] = __builtin_amdgcn_mfma_f32_16x16x32_bf16(pa[0][0], vone, lacc[0], 0, 0, 0);
        lacc[1] = __builtin_amdgcn_mfma_f32_16x16x32_bf16(pa[1][0], vone, lacc[1], 0, 0, 0);
        lacc[0] = __builtin_amdgcn_mfma_f32_16x16x32_bf16(pa[0][1], vone, lacc[0], 0, 0, 0);
        lacc[1] = __builtin_amdgcn_mfma_f32_16x16x32_bf16(pa[1][1], vone, lacc[1], 0, 0, 0);

        // PV: V fragments straight from L2, t-outer (one addr calc, imm kb2)
#pragma unroll
        for (int t = 0; t < 8; ++t) {
            const short* vp = vGp + (size_t)(t * 16) * N_ + mloc;
            bf16x8 vb0 = *(const bf16x8*)(vp);
            bf16x8 vb1 = *(const bf16x8*)(vp + 32);
            ot[0][t] = __builtin_amdgcn_mfma_f32_16x16x32_bf16(pa[0][0], vb0, ot[0][t], 0, 0, 0);
            ot[1][t] = __builtin_amdgcn_mfma_f32_16x16x32_bf16(pa[1][0], vb0, ot[1][t], 0, 0, 0);
            ot[0][t] = __builtin_amdgcn_mfma_f32_16x16x32_bf16(pa[0][1], vb1, ot[0][t], 0, 0, 0);
            ot[1][t] = __builtin_amdgcn_mfma_f32_16x16x32_bf16(pa[1][1], vb1, ot[1][t], 0, 0, 0);
        }
        __builtin_amdgcn_s_setprio(0);
    }

    // ---- epilogue: cross-kg O reduction, y->LDS, in-block wy GEMM ----
    if (s == 0) {
#pragma unroll
        for (int fr = 0; fr < 2; ++fr)
#pragma unroll
            for (int r = 0; r < 4; ++r)
                l_lds[kg][qg * 32 + fr * 16 + 4 * q + r] = lacc[fr][r];
    }
    // kg=1 dumps O partials (f32, swizzled 16B blocks) into base[0..64KB)
    if (kg == 1) {
#pragma unroll
        for (int fr = 0; fr < 2; ++fr)
#pragma unroll
            for (int t = 0; t < 8; ++t)
#pragma unroll
                for (int r = 0; r < 4; ++r) {
                    int row = qg * 32 + fr * 16 + 4 * q + r;
                    int colb = (t * 16 + s) * 4;
                    *(float*)(base + row * 512 + (colb ^ ((row & 7) << 4))) = ot[fr][t][r];
                }
    }
    __syncthreads();
    // kg=0 adds partials, writes unnormalized y bf16 -> base[65536..98304)
    if (kg == 0) {
#pragma unroll
        for (int fr = 0; fr < 2; ++fr)
#pragma unroll
            for (int t = 0; t < 8; ++t)
#pragma unroll
                for (int r = 0; r < 4; ++r) {
                    int row = qg * 32 + fr * 16 + 4 * q + r;
                    int colb = (t * 16 + s) * 4;
                    float p = *(const float*)(base + row * 512 + (colb ^ ((row & 7) << 4)));
                    float v = ot[fr][t][r] + p;
                    int byt = 65536 + row * 256 + (((t * 16 + s) * 2) ^ ((row & 7) << 4));
                    *(short*)(base + byt) = f2bf(v);
                }
    }
    __syncthreads();

    // wy GEMM: c = wave*32 + ct*16 + {s|4q+r}, n = n0 + jt*16 + s
    f32x4 acc[2][8];
#pragma unroll
    for (int ct = 0; ct < 2; ++ct)
#pragma unroll
        for (int jt = 0; jt < 8; ++jt) acc[ct][jt] = (f32x4){0.f, 0.f, 0.f, 0.f};
#pragma unroll
    for (int kb = 0; kb < 4; ++kb) {
        bf16x8 af[2];
#pragma unroll
        for (int ct = 0; ct < 2; ++ct)
            af[ct] = *(const bf16x8*)&wwb[(wave * 32 + ct * 16 + s) * 128 + kb * 32 + q * 8];
#pragma unroll
        for (int jt = 0; jt < 8; ++jt) {
            bf16x8 yb = *(const bf16x8*)(base + 65536 + kA[kb] + jt * 4096);
#pragma unroll
            for (int ct = 0; ct < 2; ++ct)
                acc[ct][jt] = __builtin_amdgcn_mfma_f32_16x16x32_bf16(af[ct], yb, acc[ct][jt], 0, 0, 0);
        }
    }
    float linv[8];
#pragma unroll
    for (int jt = 0; jt < 8; ++jt)
        linv[jt] = 1.0f / (l_lds[0][jt * 16 + s] + l_lds[1][jt * 16 + s]);
#pragma unroll
    for (int ct = 0; ct < 2; ++ct)
#pragma unroll
        for (int r = 0; r < 4; ++r) {
            int c = wave * 32 + ct * 16 + 4 * q + r;
            float bias = w_b[c];
            float s1 = 0.f, s2 = 0.f;
#pragma unroll
            for (int jt = 0; jt < 8; ++jt) {
                float v = acc[ct][jt][r] * linv[jt] + bias;
                short w = f2bf(v);
                wyh[((size_t)b * C_ + c) * N_ + n0 + jt * 16 + s] = w;
                float vr = bf2f(w);   // stats on rounded value
                s1 += vr;
                s2 += vr * vr;
            }
#pragma unroll
            for (int off = 1; off < 16; off <<= 1) {
                s1 += __shfl_xor(s1, off);
                s2 += __shfl_xor(s2, off);
            }
            if (s == 0) {  // NON-atomic per-block partials; k_fin reduces
                bnpart[(size_t)c * 256 + id] = s1;
                bnpart[(size_t)(256 + c) * 256 + id] = s2;
            }
        }
}

// ---------------- K3: reduce per-block BN partials -> bnsum ------------------
__global__ __launch_bounds__(256) void k_fin(const float* __restrict__ bnpart,
                                             float* __restrict__ bnsum) {
    int j = blockIdx.x * 256 + threadIdx.x;  // 0..511
    const float4* p = (const float4*)(bnpart + (size_t)j * 256);
    float s = 0.f;
#pragma unroll
    for (int k = 0; k < 64; ++k) {
        float4 v = p[k];
        s += (v.x + v.y) + (v.z + v.w);
    }
    bnsum[j] = s;
}

// ---------------- K5: BN finalize + apply + residual -> d_out f32 ------------
__global__ __launch_bounds__(256) void k_out(const short* __restrict__ wyh,
                                             const float* __restrict__ x,
                                             const float* __restrict__ bnsum,
                                             const float* __restrict__ gamma,
                                             const float* __restrict__ beta,
                                             float* __restrict__ out) {
    int gid = blockIdx.x * 256 + threadIdx.x;  // 8-element group index
    size_t base = (size_t)gid * 8;
    int c = (int)((base >> 12) & 255);
    const float inv = 1.0f / 32768.0f;
    float mean = bnsum[c] * inv;
    float var = bnsum[256 + c] * inv - mean * mean;
    float sc = gamma[c] * rsqrtf(var + 1e-5f);
    float sh = beta[c] - mean * sc;
    bf16x8 w = *(const bf16x8*)&wyh[base];
    float4 x0 = *(const float4*)&x[base];
    float4 x1 = *(const float4*)&x[base + 4];
    float4 o0, o1;
    o0.x = bf2f(w[0]) * sc + sh + x0.x;
    o0.y = bf2f(w[1]) * sc + sh + x0.y;
    o0.z = bf2f(w[2]) * sc + sh + x0.z;
    o0.w = bf2f(w[3]) * sc + sh + x0.w;
    o1.x = bf2f(w[4]) * sc + sh + x1.x;
    o1.y = bf2f(w[5]) * sc + sh + x1.y;
    o1.z = bf2f(w[6]) * sc + sh + x1.z;
    o1.w = bf2f(w[7]) * sc + sh + x1.w;
    *(float4*)&out[base] = o0;
    *(float4*)&out[base + 4] = o1;
}

extern "C" void kernel_launch(void* const* d_in, const int* in_sizes, int n_in,
                              void* d_out, int out_size, void* d_ws, size_t ws_size,
                              hipStream_t stream) {
    const float* x       = (const float*)d_in[0];
    const float* g_w     = (const float*)d_in[1];
    const float* g_b     = (const float*)d_in[2];
    const float* theta_w = (const float*)d_in[3];
    const float* theta_b = (const float*)d_in[4];
    const float* phi_w   = (const float*)d_in[5];
    const float* phi_b   = (const float*)d_in[6];
    const float* w_w     = (const float*)d_in[7];
    const float* w_b     = (const float*)d_in[8];
    const float* gamma   = (const float*)d_in[9];
    const float* beta    = (const float*)d_in[10];

    char* ws = (char*)d_ws;
    size_t off = 0;
    auto alloc = [&](size_t bytes) {
        void* p = ws + off;
        off += (bytes + 255) & ~(size_t)255;
        return p;
    };
    short*  wcat   = (short*)alloc((size_t)384 * 256 * 2);
    short*  wwb    = (short*)alloc((size_t)256 * 128 * 2);
    float*  bcat   = (float*)alloc((size_t)384 * 4);
    float*  bnsum  = (float*)alloc(512 * 4);                  // s1[256] | s2[256]
    float*  bnpart = (float*)alloc((size_t)512 * 256 * 4);    // per-block partials
    short*  tp     = (short*)alloc((size_t)BN_ * 256 * 2);    // theta|phi 16.78 MB
    short*  gmat   = (short*)alloc((size_t)B_ * I_ * N_ * 2); // 8.39 MB
    short*  wyh    = (short*)alloc((size_t)BN_ * C_ * 2);     // bf16 wy 16.78 MB

    k_prep<<<514, 256, 0, stream>>>(g_w, theta_w, phi_w, g_b, theta_b, phi_b, w_w,
                                    wcat, wwb, bcat);
    k_proj<<<dim3(64, 8), 256, 0, stream>>>(x, wcat, bcat, tp, gmat);
    k_attn_wy<<<256, 512, 0, stream>>>(tp, gmat, wwb, w_b, wyh, bnpart);
    k_fin<<<2, 256, 0, stream>>>(bnpart, bnsum);
    k_out<<<4096, 256, 0, stream>>>(wyh, x, bnsum, gamma, beta, (float*)d_out);
}